// Round 7
// baseline (200.515 us; speedup 1.0000x reference)
//
#include <hip/hip_runtime.h>
#include <hip/hip_bf16.h>
#include <cstdint>

typedef unsigned short u16;
typedef __attribute__((ext_vector_type(8))) short short8;
typedef __attribute__((ext_vector_type(4))) float floatx4;

#define MFMA16(a, b, c) __builtin_amdgcn_mfma_f32_16x16x32_bf16(a, b, c, 0, 0, 0)
#define LOG2E 1.4426950408889634f

__device__ __forceinline__ float fast_exp2(float x) {
#if __has_builtin(__builtin_amdgcn_exp2f)
  return __builtin_amdgcn_exp2f(x);
#else
  return exp2f(x);
#endif
}
__device__ __forceinline__ u16 f2bf(float v) {
  union { float f; unsigned u; } x; x.f = v;
  unsigned r = x.u + 0x7FFF + ((x.u >> 16) & 1);  // RNE
  return (u16)(r >> 16);
}
__device__ __forceinline__ float bf2f(u16 v) {
  union { unsigned u; float f; } x; x.u = ((unsigned)v) << 16; return x.f;
}
__device__ __forceinline__ void gload_lds16(const u16* g, u16* l) {
  __builtin_amdgcn_global_load_lds(
      (const __attribute__((address_space(1))) unsigned int*)(g),
      (__attribute__((address_space(3))) unsigned int*)(l), 16, 0, 0);
}

#if __has_builtin(__builtin_amdgcn_permlane32_swap) && __has_builtin(__builtin_amdgcn_permlane16_swap)
#define HAVE_PL 1
#endif
__device__ __forceinline__ void plswap32(unsigned& x, unsigned& y) {
#ifdef HAVE_PL
  auto r = __builtin_amdgcn_permlane32_swap(x, y, false, false);
  x = r[0]; y = r[1];
#else
  unsigned sx = (unsigned)__shfl_xor((int)x, 32, 64);
  unsigned sy = (unsigned)__shfl_xor((int)y, 32, 64);
  bool hi = (threadIdx.x & 32) != 0;
  unsigned nx = hi ? sy : x;
  unsigned ny = hi ? y : sx;
  x = nx; y = ny;
#endif
}
__device__ __forceinline__ void plswap16(unsigned& x, unsigned& y) {
#ifdef HAVE_PL
  auto r = __builtin_amdgcn_permlane16_swap(x, y, false, false);
  x = r[0]; y = r[1];
#else
  unsigned sx = (unsigned)__shfl_xor((int)x, 16, 64);
  unsigned sy = (unsigned)__shfl_xor((int)y, 16, 64);
  bool odd = (threadIdx.x & 16) != 0;
  unsigned nx = odd ? sy : x;
  unsigned ny = odd ? y : sx;
  x = nx; y = ny;
#endif
}

// ---------- mega-prep: cvt | wtrans | bias_cat | build_bm ----------
// [0,4096): cvt u/e; [4096,5120): wtrans; [5120,5128): bias; [5128,9224): build_bm
__global__ __launch_bounds__(256) void prep(
    const float* __restrict__ u, const float* __restrict__ e,
    const float* __restrict__ wq, const float* __restrict__ wk,
    const float* __restrict__ wv, const float* __restrict__ wo,
    const float* __restrict__ bq, const float* __restrict__ bk,
    const float* __restrict__ bv, const float* __restrict__ bo,
    const float* __restrict__ bpp,
    const int* __restrict__ mu, const int* __restrict__ me,
    const float* __restrict__ bw_p, const float* __restrict__ bb_p,
    u16* __restrict__ ab, u16* __restrict__ Wt,
    float* __restrict__ bias_all, u16* __restrict__ bm) {
  __shared__ float smemf[2176];   // wtrans tile (32x33) / bppT stage (128x17)
  __shared__ u16 smemo[2048];     // build_bm output stage
  const int bid = blockIdx.x, t = threadIdx.x;
  if (bid < 4096) {
    int half = bid >> 11;
    int i = ((bid & 2047) * 256 + t) * 4;
    const float* s = half ? e : u;
    float4 v = *(const float4*)(s + i);
    ushort4 o = make_ushort4(f2bf(v.x), f2bf(v.y), f2bf(v.z), f2bf(v.w));
    *(ushort4*)(ab + (size_t)half * 2097152 + i) = o;
  } else if (bid < 5120) {
    int i = bid - 4096;
    int z = i >> 8, rem = i & 255;
    const float* src = z == 0 ? wq : z == 1 ? wk : z == 2 ? wv : wo;
    float scale = z == 0 ? 0.125f * LOG2E : 1.0f;
    u16* dst = Wt + (size_t)z * 262144;
    int k0 = (rem & 15) * 32, n0 = (rem >> 4) * 32;
    int tx = t & 31, ty = t >> 5;
    float (*tl)[33] = (float(*)[33])smemf;
#pragma unroll
    for (int j = 0; j < 32; j += 8) tl[ty + j][tx] = src[(size_t)(k0 + ty + j) * 512 + n0 + tx];
    __syncthreads();
#pragma unroll
    for (int j = 0; j < 32; j += 8)
      dst[(size_t)(n0 + ty + j) * 512 + k0 + tx] = f2bf(scale * tl[tx][ty + j]);
  } else if (bid < 5128) {
    int n = (bid - 5120) * 256 + t;  // 0..2047
    float val = n < 512 ? 0.125f * LOG2E * bq[n]
              : n < 1024 ? bk[n - 512]
              : n < 1536 ? bv[n - 1024] : bo[n - 1536];
    bias_all[n] = val;
  } else {
    // build_bm: bm[sb][q16][chunk16][lane][i]; lane=(q=l15,quad), i=kb*4+r
    // value(q,k): k = chunk*64 + kb*16 + quad*4 + r
    int i = bid - 5128;
    int kcpair = i & 7, q16 = (i >> 3) & 63, sb = i >> 9;  // sb = side*4+b
    int side = sb >> 2, b = sb & 3;
    const int* mask = side ? me : mu;
    const float sw = (*bw_p) * LOG2E, sb2 = (*bb_p) * LOG2E;
    if (side) {  // stage bpp^T tile: smemf[k_loc][q_loc], k_loc<128, stride 17
#pragma unroll
      for (int ii = 0; ii < 2; ++ii) {
        int s = t + ii * 256;
        int rowk = s >> 2, c4 = (s & 3) * 4;
        float4 v = *(const float4*)(bpp + (size_t)(kcpair * 128 + rowk) * 1024 + q16 * 16 + c4);
        smemf[rowk * 17 + c4 + 0] = v.x;
        smemf[rowk * 17 + c4 + 1] = v.y;
        smemf[rowk * 17 + c4 + 2] = v.z;
        smemf[rowk * 17 + c4 + 3] = v.w;
      }
    }
    __syncthreads();
#pragma unroll
    for (int ii = 0; ii < 2; ++ii) {
      int s = t + ii * 256;
      int q_loc = s >> 5;        // 0..15
      int kq = (s & 31) * 4;     // 0..124
      int qg = q16 * 16 + q_loc;
      int4 mv = *(const int4*)(mask + ((size_t)b * 1024 + qg) * 1024 + kcpair * 128 + kq);
      float bvv[4];
      if (side) {
#pragma unroll
        for (int j = 0; j < 4; ++j) bvv[j] = smemf[(kq + j) * 17 + q_loc];
      } else {
        float4 v = *(const float4*)(bpp + (size_t)qg * 1024 + kcpair * 128 + kq);
        bvv[0] = v.x; bvv[1] = v.y; bvv[2] = v.z; bvv[3] = v.w;
      }
      int mm[4] = {mv.x, mv.y, mv.z, mv.w};
      int kc_loc = kq >> 6, k_loc = kq & 63;
      int kb = k_loc >> 4, within = k_loc & 15;
      int quad = within >> 2;
      int lane = q_loc + 16 * quad;
      u16 o[4];
#pragma unroll
      for (int j = 0; j < 4; ++j) o[j] = f2bf(mm[j] ? sw * bvv[j] + sb2 : -1e30f);
      *(ushort4*)&smemo[kc_loc * 1024 + lane * 16 + kb * 4] = *(const ushort4*)o;
    }
    __syncthreads();
    u16* dst = bm + (((size_t)sb * 64 + q16) * 16 + kcpair * 2) * 1024;
    *(short8*)(dst + t * 8) = *(const short8*)&smemo[t * 8];
  }
}

// ---------- MFMA GEMM, BK=64, 32 MFMA/barrier ----------
// Swizzle is on the GLOBAL address; LDS side of global_load_lds stays linear
// (HW uses wave-uniform base + lane*16B — per-lane LDS scatter is ignored).
// MODE 0: N=1536 -> q/k plain bf16, V -> vt transposed via LDS epilogue
// MODE 1: N=512  -> fp32 out
template <int MODE>
__global__ __launch_bounds__(256) void gemm_mfma(
    const u16* __restrict__ A, const u16* __restrict__ Bt,
    const float* __restrict__ bias, float* __restrict__ outf,
    u16* __restrict__ q_o, u16* __restrict__ k_o, u16* __restrict__ vt_o) {
  __shared__ u16 As[128 * 64];  // 16 KB
  __shared__ u16 Bs[128 * 64];  // 16 KB
  const int t = threadIdx.x, lane = t & 63, wave = t >> 6;
  const int l15 = lane & 15, quad = lane >> 4;
  const int wy = wave >> 1, wx = wave & 1;
  const int m0 = blockIdx.x * 128, n0 = blockIdx.y * 128;
  const int K = 512;

  floatx4 acc[4][4];
#pragma unroll
  for (int mi = 0; mi < 4; ++mi)
#pragma unroll
    for (int ni = 0; ni < 4; ++ni) acc[mi][ni] = (floatx4){0.f, 0.f, 0.f, 0.f};

  for (int k0 = 0; k0 < K; k0 += 64) {
    __syncthreads();
    // stage 128 rows x 8 segs (16B each); XOR swizzle applied to GLOBAL seg,
    // LDS dest linear in s => As[row*64 + seg*8] = A[row][k0 + (seg^(row&7))*8]
#pragma unroll
    for (int i = 0; i < 4; ++i) {
      int s = t + i * 256, row = s >> 3, seg = s & 7;
      gload_lds16(A + (size_t)(m0 + row) * K + k0 + ((seg ^ (row & 7)) * 8),
                  &As[s * 8]);
    }
#pragma unroll
    for (int i = 0; i < 4; ++i) {
      int s = t + i * 256, row = s >> 3, seg = s & 7;
      gload_lds16(Bt + (size_t)(n0 + row) * K + k0 + ((seg ^ (row & 7)) * 8),
                  &Bs[s * 8]);
    }
    __syncthreads();
#pragma unroll
    for (int kh = 0; kh < 2; ++kh) {
      short8 af[4], bf[4];
#pragma unroll
      for (int mi = 0; mi < 4; ++mi) {
        int row = wy * 64 + mi * 16 + l15;
        af[mi] = *(const short8*)&As[row * 64 + (((kh * 4 + quad) ^ (row & 7)) * 8)];
      }
#pragma unroll
      for (int ni = 0; ni < 4; ++ni) {
        int row = wx * 64 + ni * 16 + l15;
        bf[ni] = *(const short8*)&Bs[row * 64 + (((kh * 4 + quad) ^ (row & 7)) * 8)];
      }
#pragma unroll
      for (int mi = 0; mi < 4; ++mi)
#pragma unroll
        for (int ni = 0; ni < 4; ++ni) acc[mi][ni] = MFMA16(af[mi], bf[ni], acc[mi][ni]);
    }
  }

  if (MODE == 0 && n0 >= 1024) {
    // ---- V blocks: transpose epilogue -> vt[b][h][hd][l], coalesced rows ----
    __syncthreads();  // all waves done reading As/Bs
    u16* eb = (wave < 2) ? (As + wave * 4096) : (Bs + (wave - 2) * 4096);
    const int b = m0 >> 10, l0 = m0 & 1023;
    const int h = ((n0 - 1024) >> 6) + wx;
#pragma unroll
    for (int pass = 0; pass < 2; ++pass) {
      // write 32 n-rows (stride 72) x 64 m-cols, b64 per (mi,nj)
#pragma unroll
      for (int nj = 0; nj < 2; ++nj) {
        int ni = pass * 2 + nj;
        int np = nj * 16 + l15;  // 0..31
        int n = n0 + wx * 64 + ni * 16 + l15;
        float bv = bias[n];
        u16 o[4];
#pragma unroll
        for (int mi = 0; mi < 4; ++mi) {
#pragma unroll
          for (int r = 0; r < 4; ++r) o[r] = f2bf(acc[mi][ni][r] + bv);
          *(uint2*)&eb[np * 72 + mi * 16 + quad * 4] = *(const uint2*)o;
        }
      }
      // same-wave DS in-order: read back transposed, coalesced store
#pragma unroll
      for (int sp = 0; sp < 4; ++sp) {
        int row = sp * 8 + (lane >> 3);      // 0..31 (hd within pass)
        int col = (lane & 7) * 8;            // l offset
        short8 v = *(const short8*)&eb[row * 72 + col];
        *(short8*)(vt_o + ((size_t)(b * 8 + h) * 64 + pass * 32 + row) * 1024 +
                   l0 + wy * 64 + col) = v;
      }
    }
  } else {
#pragma unroll
    for (int mi = 0; mi < 4; ++mi)
#pragma unroll
      for (int ni = 0; ni < 4; ++ni) {
        int n = n0 + wx * 64 + ni * 16 + l15;
        float bv = bias[n];
#pragma unroll
        for (int r = 0; r < 4; ++r) {
          int m = m0 + wy * 64 + mi * 16 + quad * 4 + r;
          float v = acc[mi][ni][r] + bv;
          if (MODE == 1) {
            outf[(size_t)m * 512 + n] = v;
          } else {
            int sel = n >> 9, c = n & 511;  // block-uniform (0=q,1=k here)
            u16 hv = f2bf(v);
            if (sel == 0) q_o[(size_t)m * 512 + c] = hv;
            else k_o[(size_t)m * 512 + c] = hv;
          }
        }
      }
  }
}

// ---------- MFMA flash attention: S^T + in-register P^T (R5-proven) ----------
__global__ __launch_bounds__(256) void attn_mfma(
    const u16* __restrict__ q_all, const u16* __restrict__ k_all,
    const u16* __restrict__ vt_all, const u16* __restrict__ bm_all,
    u16* __restrict__ ctx_all) {
  __shared__ u16 Ks[2][64 * 64];
  __shared__ u16 Vs[2][64 * 64];
  __shared__ u16 epi[4][32 * 72];
  const int t = threadIdx.x, lane = t & 63, wave = t >> 6;
  const int l15 = lane & 15, quad = lane >> 4;

  const int f = blockIdx.x;
  const int g = f & 7, r0 = f >> 3;
  const int combo = g * 8 + (r0 >> 3);
  const int x = r0 & 7;
  const int side = combo >> 5, b = (combo >> 3) & 3, h = combo & 7;

  const size_t HALF = 2097152;
  const u16* Q = q_all + side * HALF;
  const u16* K = k_all + (1 - side) * HALF;
  const u16* Vt = vt_all + (1 - side) * HALF;
  const u16* bm = bm_all + side * (size_t)4194304;
  u16* ctx = ctx_all + side * HALF;
  const int qbase = x * 128 + wave * 32;
  const int q16g = qbase >> 4;

  short8 qb[2][2];
#pragma unroll
  for (int s = 0; s < 2; ++s) {
    const u16* qp = Q + (size_t)(b * 1024 + qbase + s * 16 + l15) * 512 + h * 64 + quad * 8;
    qb[s][0] = *(const short8*)qp;
    qb[s][1] = *(const short8*)(qp + 32);
  }

  short8 onesA;
#pragma unroll
  for (int j = 0; j < 8; ++j) onesA[j] = (short)0x3F80;

  floatx4 Oc[4][2];
  floatx4 Dacc[2];
#pragma unroll
  for (int s = 0; s < 2; ++s) {
    Dacc[s] = (floatx4){0.f, 0.f, 0.f, 0.f};
#pragma unroll
    for (int nb = 0; nb < 4; ++nb) Oc[nb][s] = (floatx4){0.f, 0.f, 0.f, 0.f};
  }

#define STAGE(buf, k0)                                                             \
  {                                                                                \
    _Pragma("unroll") for (int i = 0; i < 2; ++i) {                                \
      int s = t + i * 256, row = s >> 3, pseg = s & 7, lseg = pseg ^ (row & 7);    \
      gload_lds16(K + (size_t)(b * 1024 + (k0) + row) * 512 + h * 64 + lseg * 8,   \
                  &Ks[buf][s * 8]);                                                \
      gload_lds16(Vt + ((size_t)(b * 8 + h) * 64 + row) * 1024 + (k0) + lseg * 8,  \
                  &Vs[buf][s * 8]);                                                \
    }                                                                              \
  }

  STAGE(0, 0)

  for (int it = 0; it < 16; ++it) {
    const int cur = it & 1;
    __syncthreads();
    if (it < 15) STAGE(cur ^ 1, it * 64 + 64)

    short8 bmv[2][2];
#pragma unroll
    for (int s = 0; s < 2; ++s) {
      const u16* bp = bm + ((((size_t)b * 64 + q16g + s) * 16 + it) * 64 + lane) * 16;
      bmv[s][0] = *(const short8*)bp;
      bmv[s][1] = *(const short8*)(bp + 8);
    }

    floatx4 St[2][4];
#pragma unroll
    for (int s = 0; s < 2; ++s)
#pragma unroll
      for (int kb = 0; kb < 4; ++kb) St[s][kb] = (floatx4){-64.f, -64.f, -64.f, -64.f};
#pragma unroll
    for (int kb = 0; kb < 4; ++kb) {
      int krow = kb * 16 + l15;
      short8 kf0 = *(const short8*)&Ks[cur][krow * 64 + ((quad ^ (krow & 7)) * 8)];
      short8 kf1 = *(const short8*)&Ks[cur][krow * 64 + (((4 + quad) ^ (krow & 7)) * 8)];
#pragma unroll
      for (int s = 0; s < 2; ++s) {
        St[s][kb] = MFMA16(kf0, qb[s][0], St[s][kb]);
        St[s][kb] = MFMA16(kf1, qb[s][1], St[s][kb]);
      }
    }

    unsigned pka[2][4], pkb[2][4];
#pragma unroll
    for (int s = 0; s < 2; ++s)
#pragma unroll
      for (int kb = 0; kb < 4; ++kb) {
        float pv[4];
#pragma unroll
        for (int r = 0; r < 4; ++r) {
          int i = kb * 4 + r;
          float bmf = bf2f((u16)((i < 8) ? bmv[s][0][i] : bmv[s][1][i - 8]));
          pv[r] = fast_exp2(St[s][kb][r] + bmf);
        }
        union { __hip_bfloat162 h; unsigned u; } c0, c1;
        c0.h = __float22bfloat162_rn(make_float2(pv[0], pv[1]));
        c1.h = __float22bfloat162_rn(make_float2(pv[2], pv[3]));
        pka[s][kb] = c0.u;
        pkb[s][kb] = c1.u;
      }

    short8 Pb[2][2];
#pragma unroll
    for (int s = 0; s < 2; ++s)
#pragma unroll
      for (int ks = 0; ks < 2; ++ks) {
        unsigned a0 = pka[s][2 * ks], a1 = pka[s][2 * ks + 1];
        unsigned b0 = pkb[s][2 * ks], b1 = pkb[s][2 * ks + 1];
        plswap32(a0, a1); plswap16(a0, a1);
        plswap32(b0, b1); plswap16(b0, b1);
        union { short8 s8; unsigned u[4]; } fb;
        fb.u[0] = a0; fb.u[1] = b0; fb.u[2] = a1; fb.u[3] = b1;
        Pb[s][ks] = fb.s8;
        Dacc[s] = MFMA16(onesA, fb.s8, Dacc[s]);
      }

#pragma unroll
    for (int nb = 0; nb < 4; ++nb) {
      int vrow = nb * 16 + l15;
#pragma unroll
      for (int ks = 0; ks < 2; ++ks) {
        short8 vf = *(const short8*)&Vs[cur][vrow * 64 + ((((ks * 4 + quad)) ^ (vrow & 7)) * 8)];
        Oc[nb][0] = MFMA16(vf, Pb[0][ks], Oc[nb][0]);
        Oc[nb][1] = MFMA16(vf, Pb[1][ks], Oc[nb][1]);
      }
    }
  }

  u16* eb = &epi[wave][0];
#pragma unroll
  for (int s = 0; s < 2; ++s) {
    float dv = Dacc[s][0];
    float inv = dv > 0.f ? 1.f / dv : 0.f;
#pragma unroll
    for (int nb = 0; nb < 4; ++nb) {
      union { __hip_bfloat162 h; unsigned u; } w0, w1;
      w0.h = __float22bfloat162_rn(make_float2(Oc[nb][s][0] * inv, Oc[nb][s][1] * inv));
      w1.h = __float22bfloat162_rn(make_float2(Oc[nb][s][2] * inv, Oc[nb][s][3] * inv));
      union { unsigned u[2]; unsigned long long ull; } pk;
      pk.u[0] = w0.u; pk.u[1] = w1.u;
      *(unsigned long long*)&eb[(s * 16 + l15) * 72 + nb * 16 + quad * 4] = pk.ull;
    }
  }
#pragma unroll
  for (int p = 0; p < 4; ++p) {
    int row = p * 8 + (lane >> 3);
    int cs = (lane & 7) * 8;
    short8 v = *(const short8*)&eb[row * 72 + cs];
    *(short8*)(ctx + (size_t)(b * 1024 + qbase + row) * 512 + h * 64 + cs) = v;
  }
}

extern "C" void kernel_launch(void* const* d_in, const int* in_sizes, int n_in,
                              void* d_out, int out_size, void* d_ws, size_t ws_size,
                              hipStream_t stream) {
  const float* u_enc = (const float*)d_in[0];
  const float* e_enc = (const float*)d_in[1];
  const float* logit_bpp = (const float*)d_in[2];
  const int* ue_mask = (const int*)d_in[3];
  const int* eu_mask = (const int*)d_in[4];
  const float* wq_k = (const float*)d_in[5];
  const float* wq_b = (const float*)d_in[6];
  const float* wk_k = (const float*)d_in[7];
  const float* wk_b = (const float*)d_in[8];
  const float* wv_k = (const float*)d_in[9];
  const float* wv_b = (const float*)d_in[10];
  const float* wo_k = (const float*)d_in[11];
  const float* wo_b = (const float*)d_in[12];
  const float* bpp_w = (const float*)d_in[13];
  const float* bpp_b = (const float*)d_in[14];

  float* out = (float*)d_out;

  u16* ws16 = (u16*)d_ws;
  u16* ab    = ws16;                     // 4,194,304 u16
  u16* Wt    = ab + 4194304;             // 1,048,576
  u16* q_all = Wt + 1048576;             // 4,194,304
  u16* k_all = q_all + 4194304;          // 4,194,304
  u16* vt    = k_all + 4194304;          // 4,194,304  (written directly by gemm<0>)
  u16* ctx   = vt + 4194304;             // 4,194,304
  u16* bm    = ctx + 4194304;            // 8,388,608
  float* bias_all = (float*)(bm + 8388608);  // 2048 f32

  prep<<<9224, 256, 0, stream>>>(u_enc, e_enc, wq_k, wk_k, wv_k, wo_k,
                                 wq_b, wk_b, wv_b, wo_b, logit_bpp,
                                 ue_mask, eu_mask, bpp_w, bpp_b,
                                 ab, Wt, bias_all, bm);
  gemm_mfma<0><<<dim3(64, 12), 256, 0, stream>>>(ab, Wt, bias_all, nullptr,
                                                 q_all, k_all, vt);
  attn_mfma<<<512, 256, 0, stream>>>(q_all, k_all, vt, bm, ctx);
  gemm_mfma<1><<<dim3(64, 4), 256, 0, stream>>>(ctx, Wt + 786432, bias_all + 1536,
                                                out, nullptr, nullptr, nullptr);
}

// Round 8
// 198.459 us; speedup vs baseline: 1.0104x; 1.0104x over previous
//
#include <hip/hip_runtime.h>
#include <hip/hip_bf16.h>
#include <cstdint>

typedef unsigned short u16;
typedef __attribute__((ext_vector_type(8))) short short8;
typedef __attribute__((ext_vector_type(4))) float floatx4;

#define MFMA16(a, b, c) __builtin_amdgcn_mfma_f32_16x16x32_bf16(a, b, c, 0, 0, 0)
#define LOG2E 1.4426950408889634f

__device__ __forceinline__ float fast_exp2(float x) {
#if __has_builtin(__builtin_amdgcn_exp2f)
  return __builtin_amdgcn_exp2f(x);
#else
  return exp2f(x);
#endif
}
__device__ __forceinline__ u16 f2bf(float v) {
  union { float f; unsigned u; } x; x.f = v;
  unsigned r = x.u + 0x7FFF + ((x.u >> 16) & 1);  // RNE
  return (u16)(r >> 16);
}
__device__ __forceinline__ float bf2f(u16 v) {
  union { unsigned u; float f; } x; x.u = ((unsigned)v) << 16; return x.f;
}
__device__ __forceinline__ void gload_lds16(const u16* g, u16* l) {
  __builtin_amdgcn_global_load_lds(
      (const __attribute__((address_space(1))) unsigned int*)(g),
      (__attribute__((address_space(3))) unsigned int*)(l), 16, 0, 0);
}

#if __has_builtin(__builtin_amdgcn_permlane32_swap) && __has_builtin(__builtin_amdgcn_permlane16_swap)
#define HAVE_PL 1
#endif
__device__ __forceinline__ void plswap32(unsigned& x, unsigned& y) {
#ifdef HAVE_PL
  auto r = __builtin_amdgcn_permlane32_swap(x, y, false, false);
  x = r[0]; y = r[1];
#else
  unsigned sx = (unsigned)__shfl_xor((int)x, 32, 64);
  unsigned sy = (unsigned)__shfl_xor((int)y, 32, 64);
  bool hi = (threadIdx.x & 32) != 0;
  unsigned nx = hi ? sy : x;
  unsigned ny = hi ? y : sx;
  x = nx; y = ny;
#endif
}
__device__ __forceinline__ void plswap16(unsigned& x, unsigned& y) {
#ifdef HAVE_PL
  auto r = __builtin_amdgcn_permlane16_swap(x, y, false, false);
  x = r[0]; y = r[1];
#else
  unsigned sx = (unsigned)__shfl_xor((int)x, 16, 64);
  unsigned sy = (unsigned)__shfl_xor((int)y, 16, 64);
  bool odd = (threadIdx.x & 16) != 0;
  unsigned nx = odd ? sy : x;
  unsigned ny = odd ? y : sx;
  x = nx; y = ny;
#endif
}

// ---------- mega-prep: cvt | wtrans | bias_cat | build_bm ----------
// [0,4096): cvt u/e; [4096,5120): wtrans; [5120,5128): bias; [5128,9224): build_bm
__global__ __launch_bounds__(256) void prep(
    const float* __restrict__ u, const float* __restrict__ e,
    const float* __restrict__ wq, const float* __restrict__ wk,
    const float* __restrict__ wv, const float* __restrict__ wo,
    const float* __restrict__ bq, const float* __restrict__ bk,
    const float* __restrict__ bv, const float* __restrict__ bo,
    const float* __restrict__ bpp,
    const int* __restrict__ mu, const int* __restrict__ me,
    const float* __restrict__ bw_p, const float* __restrict__ bb_p,
    u16* __restrict__ ab, u16* __restrict__ Wt,
    float* __restrict__ bias_all, u16* __restrict__ bm) {
  __shared__ float smemf[2176];   // wtrans tile (32x33) / bppT stage (128x17)
  __shared__ u16 smemo[2048];     // build_bm output stage
  const int bid = blockIdx.x, t = threadIdx.x;
  if (bid < 4096) {
    int half = bid >> 11;
    int i = ((bid & 2047) * 256 + t) * 4;
    const float* s = half ? e : u;
    float4 v = *(const float4*)(s + i);
    ushort4 o = make_ushort4(f2bf(v.x), f2bf(v.y), f2bf(v.z), f2bf(v.w));
    *(ushort4*)(ab + (size_t)half * 2097152 + i) = o;
  } else if (bid < 5120) {
    int i = bid - 4096;
    int z = i >> 8, rem = i & 255;
    const float* src = z == 0 ? wq : z == 1 ? wk : z == 2 ? wv : wo;
    float scale = z == 0 ? 0.125f * LOG2E : 1.0f;
    u16* dst = Wt + (size_t)z * 262144;
    int k0 = (rem & 15) * 32, n0 = (rem >> 4) * 32;
    int tx = t & 31, ty = t >> 5;
    float (*tl)[33] = (float(*)[33])smemf;
#pragma unroll
    for (int j = 0; j < 32; j += 8) tl[ty + j][tx] = src[(size_t)(k0 + ty + j) * 512 + n0 + tx];
    __syncthreads();
#pragma unroll
    for (int j = 0; j < 32; j += 8)
      dst[(size_t)(n0 + ty + j) * 512 + k0 + tx] = f2bf(scale * tl[tx][ty + j]);
  } else if (bid < 5128) {
    int n = (bid - 5120) * 256 + t;  // 0..2047
    float val = n < 512 ? 0.125f * LOG2E * bq[n]
              : n < 1024 ? bk[n - 512]
              : n < 1536 ? bv[n - 1024] : bo[n - 1536];
    bias_all[n] = val;
  } else {
    // build_bm: bm[sb][q16][chunk16][lane][i]; lane=(q=l15,quad), i=kb*4+r
    // value(q,k): k = chunk*64 + kb*16 + quad*4 + r
    int i = bid - 5128;
    int kcpair = i & 7, q16 = (i >> 3) & 63, sb = i >> 9;  // sb = side*4+b
    int side = sb >> 2, b = sb & 3;
    const int* mask = side ? me : mu;
    const float sw = (*bw_p) * LOG2E, sb2 = (*bb_p) * LOG2E;
    if (side) {  // stage bpp^T tile: smemf[k_loc][q_loc], k_loc<128, stride 17
#pragma unroll
      for (int ii = 0; ii < 2; ++ii) {
        int s = t + ii * 256;
        int rowk = s >> 2, c4 = (s & 3) * 4;
        float4 v = *(const float4*)(bpp + (size_t)(kcpair * 128 + rowk) * 1024 + q16 * 16 + c4);
        smemf[rowk * 17 + c4 + 0] = v.x;
        smemf[rowk * 17 + c4 + 1] = v.y;
        smemf[rowk * 17 + c4 + 2] = v.z;
        smemf[rowk * 17 + c4 + 3] = v.w;
      }
    }
    __syncthreads();
#pragma unroll
    for (int ii = 0; ii < 2; ++ii) {
      int s = t + ii * 256;
      int q_loc = s >> 5;        // 0..15
      int kq = (s & 31) * 4;     // 0..124
      int qg = q16 * 16 + q_loc;
      int4 mv = *(const int4*)(mask + ((size_t)b * 1024 + qg) * 1024 + kcpair * 128 + kq);
      float bvv[4];
      if (side) {
#pragma unroll
        for (int j = 0; j < 4; ++j) bvv[j] = smemf[(kq + j) * 17 + q_loc];
      } else {
        float4 v = *(const float4*)(bpp + (size_t)qg * 1024 + kcpair * 128 + kq);
        bvv[0] = v.x; bvv[1] = v.y; bvv[2] = v.z; bvv[3] = v.w;
      }
      int mm[4] = {mv.x, mv.y, mv.z, mv.w};
      int kc_loc = kq >> 6, k_loc = kq & 63;
      int kb = k_loc >> 4, within = k_loc & 15;
      int quad = within >> 2;
      int lane = q_loc + 16 * quad;
      u16 o[4];
#pragma unroll
      for (int j = 0; j < 4; ++j) o[j] = f2bf(mm[j] ? sw * bvv[j] + sb2 : -1e30f);
      *(ushort4*)&smemo[kc_loc * 1024 + lane * 16 + kb * 4] = *(const ushort4*)o;
    }
    __syncthreads();
    u16* dst = bm + (((size_t)sb * 64 + q16) * 16 + kcpair * 2) * 1024;
    *(short8*)(dst + t * 8) = *(const short8*)&smemo[t * 8];
  }
}

// ---------- MFMA GEMM, BK=64, 32 MFMA/barrier ----------
// Swizzle on the GLOBAL address; LDS side of global_load_lds stays linear
// (HW uses wave-uniform base + lane*16B — per-lane LDS scatter is ignored).
// MODE 0: BN=128, N=1536 -> q/k plain bf16, V -> vt transposed via LDS epilogue
// MODE 1: BN=64,  N=512  -> fp32 out (512 blocks = 2/CU for occupancy)
template <int MODE>
__global__ __launch_bounds__(256) void gemm_mfma(
    const u16* __restrict__ A, const u16* __restrict__ Bt,
    const float* __restrict__ bias, float* __restrict__ outf,
    u16* __restrict__ q_o, u16* __restrict__ k_o, u16* __restrict__ vt_o) {
  constexpr int BN = (MODE == 1) ? 64 : 128;   // block n-width
  constexpr int NT = (MODE == 1) ? 2 : 4;      // n-tiles per wave
  __shared__ u16 As[128 * 64];                 // 16 KB
  __shared__ u16 Bs[BN * 64];                  // 8/16 KB
  const int t = threadIdx.x, lane = t & 63, wave = t >> 6;
  const int l15 = lane & 15, quad = lane >> 4;
  const int wy = wave >> 1, wx = wave & 1;
  const int m0 = blockIdx.x * 128, n0 = blockIdx.y * BN;
  const int K = 512;

  floatx4 acc[4][NT];
#pragma unroll
  for (int mi = 0; mi < 4; ++mi)
#pragma unroll
    for (int ni = 0; ni < NT; ++ni) acc[mi][ni] = (floatx4){0.f, 0.f, 0.f, 0.f};

  for (int k0 = 0; k0 < K; k0 += 64) {
    __syncthreads();
    // stage rows x 8 segs (16B each); XOR swizzle applied to GLOBAL seg,
    // LDS dest linear in s => As[row*64 + seg*8] = A[row][k0 + (seg^(row&7))*8]
#pragma unroll
    for (int i = 0; i < 4; ++i) {
      int s = t + i * 256, row = s >> 3, seg = s & 7;
      gload_lds16(A + (size_t)(m0 + row) * K + k0 + ((seg ^ (row & 7)) * 8),
                  &As[s * 8]);
    }
#pragma unroll
    for (int i = 0; i < BN / 32; ++i) {
      int s = t + i * 256, row = s >> 3, seg = s & 7;
      gload_lds16(Bt + (size_t)(n0 + row) * K + k0 + ((seg ^ (row & 7)) * 8),
                  &Bs[s * 8]);
    }
    __syncthreads();
#pragma unroll
    for (int kh = 0; kh < 2; ++kh) {
      short8 af[4], bf[NT];
#pragma unroll
      for (int mi = 0; mi < 4; ++mi) {
        int row = wy * 64 + mi * 16 + l15;
        af[mi] = *(const short8*)&As[row * 64 + (((kh * 4 + quad) ^ (row & 7)) * 8)];
      }
#pragma unroll
      for (int ni = 0; ni < NT; ++ni) {
        int row = wx * (16 * NT) + ni * 16 + l15;
        bf[ni] = *(const short8*)&Bs[row * 64 + (((kh * 4 + quad) ^ (row & 7)) * 8)];
      }
#pragma unroll
      for (int mi = 0; mi < 4; ++mi)
#pragma unroll
        for (int ni = 0; ni < NT; ++ni) acc[mi][ni] = MFMA16(af[mi], bf[ni], acc[mi][ni]);
    }
  }

  if (MODE == 0 && n0 >= 1024) {
    // ---- V blocks: transpose epilogue -> vt[b][h][hd][l], coalesced rows ----
    __syncthreads();  // all waves done reading As/Bs
    u16* eb = (wave < 2) ? (As + wave * 4096) : (Bs + (wave - 2) * 4096);
    const int b = m0 >> 10, l0 = m0 & 1023;
    const int h = ((n0 - 1024) >> 6) + wx;
#pragma unroll
    for (int pass = 0; pass < 2; ++pass) {
#pragma unroll
      for (int nj = 0; nj < 2; ++nj) {
        int ni = pass * 2 + nj;
        int np = nj * 16 + l15;  // 0..31
        int n = n0 + wx * 64 + ni * 16 + l15;
        float bv = bias[n];
        u16 o[4];
#pragma unroll
        for (int mi = 0; mi < 4; ++mi) {
#pragma unroll
          for (int r = 0; r < 4; ++r) o[r] = f2bf(acc[mi][ni][r] + bv);
          *(uint2*)&eb[np * 72 + mi * 16 + quad * 4] = *(const uint2*)o;
        }
      }
      // same-wave DS in-order: read back transposed, coalesced store
#pragma unroll
      for (int sp = 0; sp < 4; ++sp) {
        int row = sp * 8 + (lane >> 3);      // 0..31 (hd within pass)
        int col = (lane & 7) * 8;            // l offset
        short8 v = *(const short8*)&eb[row * 72 + col];
        *(short8*)(vt_o + ((size_t)(b * 8 + h) * 64 + pass * 32 + row) * 1024 +
                   l0 + wy * 64 + col) = v;
      }
    }
  } else {
#pragma unroll
    for (int mi = 0; mi < 4; ++mi)
#pragma unroll
      for (int ni = 0; ni < NT; ++ni) {
        int n = n0 + wx * (16 * NT) + ni * 16 + l15;
        float bv = bias[n];
#pragma unroll
        for (int r = 0; r < 4; ++r) {
          int m = m0 + wy * 64 + mi * 16 + quad * 4 + r;
          float v = acc[mi][ni][r] + bv;
          if (MODE == 1) {
            outf[(size_t)m * 512 + n] = v;
          } else {
            int sel = n >> 9, c = n & 511;  // block-uniform (0=q,1=k here)
            u16 hv = f2bf(v);
            if (sel == 0) q_o[(size_t)m * 512 + c] = hv;
            else k_o[(size_t)m * 512 + c] = hv;
          }
        }
      }
  }
}

// ---------- MFMA flash attention: S^T + in-register P^T (R5/R7-proven) ----------
__global__ __launch_bounds__(256) void attn_mfma(
    const u16* __restrict__ q_all, const u16* __restrict__ k_all,
    const u16* __restrict__ vt_all, const u16* __restrict__ bm_all,
    u16* __restrict__ ctx_all) {
  __shared__ u16 Ks[2][64 * 64];
  __shared__ u16 Vs[2][64 * 64];
  __shared__ u16 epi[4][32 * 72];
  const int t = threadIdx.x, lane = t & 63, wave = t >> 6;
  const int l15 = lane & 15, quad = lane >> 4;

  const int f = blockIdx.x;
  const int g = f & 7, r0 = f >> 3;
  const int combo = g * 8 + (r0 >> 3);
  const int x = r0 & 7;
  const int side = combo >> 5, b = (combo >> 3) & 3, h = combo & 7;

  const size_t HALF = 2097152;
  const u16* Q = q_all + side * HALF;
  const u16* K = k_all + (1 - side) * HALF;
  const u16* Vt = vt_all + (1 - side) * HALF;
  const u16* bm = bm_all + side * (size_t)4194304;
  u16* ctx = ctx_all + side * HALF;
  const int qbase = x * 128 + wave * 32;
  const int q16g = qbase >> 4;

  short8 qb[2][2];
#pragma unroll
  for (int s = 0; s < 2; ++s) {
    const u16* qp = Q + (size_t)(b * 1024 + qbase + s * 16 + l15) * 512 + h * 64 + quad * 8;
    qb[s][0] = *(const short8*)qp;
    qb[s][1] = *(const short8*)(qp + 32);
  }

  short8 onesA;
#pragma unroll
  for (int j = 0; j < 8; ++j) onesA[j] = (short)0x3F80;

  floatx4 Oc[4][2];
  floatx4 Dacc[2];
#pragma unroll
  for (int s = 0; s < 2; ++s) {
    Dacc[s] = (floatx4){0.f, 0.f, 0.f, 0.f};
#pragma unroll
    for (int nb = 0; nb < 4; ++nb) Oc[nb][s] = (floatx4){0.f, 0.f, 0.f, 0.f};
  }

#define STAGE(buf, k0)                                                             \
  {                                                                                \
    _Pragma("unroll") for (int i = 0; i < 2; ++i) {                                \
      int s = t + i * 256, row = s >> 3, pseg = s & 7, lseg = pseg ^ (row & 7);    \
      gload_lds16(K + (size_t)(b * 1024 + (k0) + row) * 512 + h * 64 + lseg * 8,   \
                  &Ks[buf][s * 8]);                                                \
      gload_lds16(Vt + ((size_t)(b * 8 + h) * 64 + row) * 1024 + (k0) + lseg * 8,  \
                  &Vs[buf][s * 8]);                                                \
    }                                                                              \
  }

  STAGE(0, 0)

  for (int it = 0; it < 16; ++it) {
    const int cur = it & 1;
    __syncthreads();
    if (it < 15) STAGE(cur ^ 1, it * 64 + 64)

    short8 bmv[2][2];
#pragma unroll
    for (int s = 0; s < 2; ++s) {
      const u16* bp = bm + ((((size_t)b * 64 + q16g + s) * 16 + it) * 64 + lane) * 16;
      bmv[s][0] = *(const short8*)bp;
      bmv[s][1] = *(const short8*)(bp + 8);
    }

    floatx4 St[2][4];
#pragma unroll
    for (int s = 0; s < 2; ++s)
#pragma unroll
      for (int kb = 0; kb < 4; ++kb) St[s][kb] = (floatx4){-64.f, -64.f, -64.f, -64.f};
#pragma unroll
    for (int kb = 0; kb < 4; ++kb) {
      int krow = kb * 16 + l15;
      short8 kf0 = *(const short8*)&Ks[cur][krow * 64 + ((quad ^ (krow & 7)) * 8)];
      short8 kf1 = *(const short8*)&Ks[cur][krow * 64 + (((4 + quad) ^ (krow & 7)) * 8)];
#pragma unroll
      for (int s = 0; s < 2; ++s) {
        St[s][kb] = MFMA16(kf0, qb[s][0], St[s][kb]);
        St[s][kb] = MFMA16(kf1, qb[s][1], St[s][kb]);
      }
    }

    unsigned pka[2][4], pkb[2][4];
#pragma unroll
    for (int s = 0; s < 2; ++s)
#pragma unroll
      for (int kb = 0; kb < 4; ++kb) {
        float pv[4];
#pragma unroll
        for (int r = 0; r < 4; ++r) {
          int i = kb * 4 + r;
          float bmf = bf2f((u16)((i < 8) ? bmv[s][0][i] : bmv[s][1][i - 8]));
          pv[r] = fast_exp2(St[s][kb][r] + bmf);
        }
        union { __hip_bfloat162 h; unsigned u; } c0, c1;
        c0.h = __float22bfloat162_rn(make_float2(pv[0], pv[1]));
        c1.h = __float22bfloat162_rn(make_float2(pv[2], pv[3]));
        pka[s][kb] = c0.u;
        pkb[s][kb] = c1.u;
      }

    short8 Pb[2][2];
#pragma unroll
    for (int s = 0; s < 2; ++s)
#pragma unroll
      for (int ks = 0; ks < 2; ++ks) {
        unsigned a0 = pka[s][2 * ks], a1 = pka[s][2 * ks + 1];
        unsigned b0 = pkb[s][2 * ks], b1 = pkb[s][2 * ks + 1];
        plswap32(a0, a1); plswap16(a0, a1);
        plswap32(b0, b1); plswap16(b0, b1);
        union { short8 s8; unsigned u[4]; } fb;
        fb.u[0] = a0; fb.u[1] = b0; fb.u[2] = a1; fb.u[3] = b1;
        Pb[s][ks] = fb.s8;
        Dacc[s] = MFMA16(onesA, fb.s8, Dacc[s]);
      }

#pragma unroll
    for (int nb = 0; nb < 4; ++nb) {
      int vrow = nb * 16 + l15;
#pragma unroll
      for (int ks = 0; ks < 2; ++ks) {
        short8 vf = *(const short8*)&Vs[cur][vrow * 64 + ((((ks * 4 + quad)) ^ (vrow & 7)) * 8)];
        Oc[nb][0] = MFMA16(vf, Pb[0][ks], Oc[nb][0]);
        Oc[nb][1] = MFMA16(vf, Pb[1][ks], Oc[nb][1]);
      }
    }
  }

  u16* eb = &epi[wave][0];
#pragma unroll
  for (int s = 0; s < 2; ++s) {
    float dv = Dacc[s][0];
    float inv = dv > 0.f ? 1.f / dv : 0.f;
#pragma unroll
    for (int nb = 0; nb < 4; ++nb) {
      union { __hip_bfloat162 h; unsigned u; } w0, w1;
      w0.h = __float22bfloat162_rn(make_float2(Oc[nb][s][0] * inv, Oc[nb][s][1] * inv));
      w1.h = __float22bfloat162_rn(make_float2(Oc[nb][s][2] * inv, Oc[nb][s][3] * inv));
      union { unsigned u[2]; unsigned long long ull; } pk;
      pk.u[0] = w0.u; pk.u[1] = w1.u;
      *(unsigned long long*)&eb[(s * 16 + l15) * 72 + nb * 16 + quad * 4] = pk.ull;
    }
  }
#pragma unroll
  for (int p = 0; p < 4; ++p) {
    int row = p * 8 + (lane >> 3);
    int cs = (lane & 7) * 8;
    short8 v = *(const short8*)&eb[row * 72 + cs];
    *(short8*)(ctx + (size_t)(b * 1024 + qbase + row) * 512 + h * 64 + cs) = v;
  }
}

extern "C" void kernel_launch(void* const* d_in, const int* in_sizes, int n_in,
                              void* d_out, int out_size, void* d_ws, size_t ws_size,
                              hipStream_t stream) {
  const float* u_enc = (const float*)d_in[0];
  const float* e_enc = (const float*)d_in[1];
  const float* logit_bpp = (const float*)d_in[2];
  const int* ue_mask = (const int*)d_in[3];
  const int* eu_mask = (const int*)d_in[4];
  const float* wq_k = (const float*)d_in[5];
  const float* wq_b = (const float*)d_in[6];
  const float* wk_k = (const float*)d_in[7];
  const float* wk_b = (const float*)d_in[8];
  const float* wv_k = (const float*)d_in[9];
  const float* wv_b = (const float*)d_in[10];
  const float* wo_k = (const float*)d_in[11];
  const float* wo_b = (const float*)d_in[12];
  const float* bpp_w = (const float*)d_in[13];
  const float* bpp_b = (const float*)d_in[14];

  float* out = (float*)d_out;

  u16* ws16 = (u16*)d_ws;
  u16* ab    = ws16;                     // 4,194,304 u16
  u16* Wt    = ab + 4194304;             // 1,048,576
  u16* q_all = Wt + 1048576;             // 4,194,304
  u16* k_all = q_all + 4194304;          // 4,194,304
  u16* vt    = k_all + 4194304;          // 4,194,304  (written directly by gemm<0>)
  u16* ctx   = vt + 4194304;             // 4,194,304
  u16* bm    = ctx + 4194304;            // 8,388,608
  float* bias_all = (float*)(bm + 8388608);  // 2048 f32

  prep<<<9224, 256, 0, stream>>>(u_enc, e_enc, wq_k, wk_k, wv_k, wo_k,
                                 wq_b, wk_b, wv_b, wo_b, logit_bpp,
                                 ue_mask, eu_mask, bpp_w, bpp_b,
                                 ab, Wt, bias_all, bm);
  gemm_mfma<0><<<dim3(64, 12), 256, 0, stream>>>(ab, Wt, bias_all, nullptr,
                                                 q_all, k_all, vt);
  attn_mfma<<<512, 256, 0, stream>>>(q_all, k_all, vt, bm, ctx);
  gemm_mfma<1><<<dim3(64, 8), 256, 0, stream>>>(ctx, Wt + 786432, bias_all + 1536,
                                                out, nullptr, nullptr, nullptr);
}